// Round 7
// baseline (117.412 us; speedup 1.0000x reference)
//
#include <hip/hip_runtime.h>

#define NB 2048
#define NJ 22
#define ND 128
#define NBAT 8
#define NBLK (NB / NBAT)     // 256 blocks = 1 per CU
#define JD (NJ * ND)         // 2816 floats per batch
#define ROW4 (JD / 4)        // 704 float4 per i-row

typedef float f32x4 __attribute__((ext_vector_type(4)));

// Raw barrier: drains LDS ops only; global stores stay in flight across it.
__device__ __forceinline__ void bar_lgkm() {
  asm volatile("s_waitcnt lgkmcnt(0)" ::: "memory");
  __builtin_amdgcn_s_barrier();
  __builtin_amdgcn_sched_barrier(0);
}

// out[b][i][j][e] = Y[b][j][e] - Y[b][i][e] + bias[e],  Y = src @ W^T
// Persistent 1 block/CU; ALL 8 src batches preloaded to LDS -> steady state
// has zero global reads; stores of batch k drain under GEMM of batch k+1.
__global__ __launch_bounds__(256, 1) void see_kernel(
    const float* __restrict__ src, const float* __restrict__ W,
    const float* __restrict__ bias, float* __restrict__ out) {
  __shared__ float srcS[NBAT][JD];  // 90 KB: entire block's src slice
  __shared__ float YS[JD];          // 11 KB

  const int t = threadIdx.x;
  const size_t b0 = (size_t)blockIdx.x * NBAT;

  // ---- prologue: stage all 8 batches of src -> LDS (one-time reads) ----
#pragma unroll
  for (int bb = 0; bb < NBAT; ++bb) {
    const f32x4* g = reinterpret_cast<const f32x4*>(src + (b0 + bb) * JD);
    f32x4* l = reinterpret_cast<f32x4*>(&srcS[bb][0]);
    f32x4 r0 = g[t], r1 = g[t + 256], r2 = {0, 0, 0, 0};
    if (t < 192) r2 = g[t + 512];
    l[t] = r0; l[t + 256] = r1;
    if (t < 192) l[t + 512] = r2;
  }

  // ---- W row for this thread's feature e, full d-range (once, x8 reuse) ----
  const int e  = t & 127;          // feature owned
  const int jb = (t >> 7) * 11;    // j-base: waves 0-1 -> j 0..10, waves 2-3 -> 11..21
  float w[128];
  {
    const f32x4* Wrow = reinterpret_cast<const f32x4*>(W + e * ND);
#pragma unroll
    for (int k = 0; k < 32; ++k) {
      f32x4 v = Wrow[k];
      w[4 * k + 0] = v.x; w[4 * k + 1] = v.y;
      w[4 * k + 2] = v.z; w[4 * k + 3] = v.w;
    }
  }
  const int e4 = t & 31;   // epilogue float4 column
  const int j0 = t >> 5;   // epilogue rows {j0, j0+8, j0+16}
  const f32x4 bb4 = reinterpret_cast<const f32x4*>(bias)[e4];

  for (int bi = 0; bi < NBAT; ++bi) {
    // top barrier: srcS ready (bi=0) / previous epilogue's YS reads done
    bar_lgkm();

    // ---- GEMM: acc[jj] = src[b][jb+jj][:] . W[e][:]  (broadcast LDS reads) ----
    float acc[11];
#pragma unroll
    for (int jj = 0; jj < 11; ++jj) {
      const f32x4* s4 = reinterpret_cast<const f32x4*>(&srcS[bi][(jb + jj) * ND]);
      float a = 0.f;
#pragma unroll
      for (int k = 0; k < 32; ++k) {
        f32x4 s = s4[k];  // wave-uniform address -> broadcast, conflict-free
        a += s.x * w[4 * k + 0];
        a += s.y * w[4 * k + 1];
        a += s.z * w[4 * k + 2];
        a += s.w * w[4 * k + 3];
      }
      acc[jj] = a;
    }
#pragma unroll
    for (int jj = 0; jj < 11; ++jj) YS[(jb + jj) * ND + e] = acc[jj];

    bar_lgkm();  // YS complete

    // ---- epilogue: out[b][i][j][e] = YS[j][e] - YS[i][e] + bias[e] ----
    const f32x4* YS4 = reinterpret_cast<const f32x4*>(YS);
    f32x4 yj0 = YS4[j0 * 32 + e4] + bb4;
    f32x4 yj1 = YS4[(j0 + 8) * 32 + e4] + bb4;
    f32x4 yj2 = {0, 0, 0, 0};
    if (j0 < 6) yj2 = YS4[(j0 + 16) * 32 + e4] + bb4;

    f32x4* outB4 = reinterpret_cast<f32x4*>(out + (b0 + bi) * (size_t)NJ * JD);
    for (int ii = 0; ii < NJ; ++ii) {
      f32x4 yi = YS4[ii * 32 + e4];
      f32x4* outRow4 = outB4 + (size_t)ii * ROW4;
      outRow4[t] = yj0 - yi;
      outRow4[t + 256] = yj1 - yi;
      if (j0 < 6) outRow4[t + 512] = yj2 - yi;
    }
    // no barrier here; next iteration's top barrier protects YS overwrite,
    // and no vmcnt wait anywhere -> stores keep draining under next GEMM.
  }
}

extern "C" void kernel_launch(void* const* d_in, const int* in_sizes, int n_in,
                              void* d_out, int out_size, void* d_ws, size_t ws_size,
                              hipStream_t stream) {
  const float* src  = (const float*)d_in[0];  // [2048, 22, 128] f32
  const float* W    = (const float*)d_in[1];  // [128, 128] f32, W[e][d]
  const float* bias = (const float*)d_in[2];  // [128] f32
  float* out = (float*)d_out;                 // [2048, 22, 22, 128] f32

  see_kernel<<<NBLK, 256, 0, stream>>>(src, W, bias, out);
}